// Round 6
// baseline (61581.311 us; speedup 1.0000x reference)
//
#include <hip/hip_runtime.h>

#define H    50
#define T    65536
#define NTHREADS 256

// ws layout (floats)
#define WC1_OFF 0        // 200*64
#define WC2_OFF 12800    // 200*128

// Prep (unchanged from R5): permute rows (r' = j*4+gate), pad cols, fold
// biases into cols 58 (Wc1) / 100 (Wc2).
__global__ void prep_kernel(const float* __restrict__ Wih1, const float* __restrict__ Whh1,
                            const float* __restrict__ bih1, const float* __restrict__ bhh1,
                            const float* __restrict__ Wih2, const float* __restrict__ Whh2,
                            const float* __restrict__ bih2, const float* __restrict__ bhh2,
                            float* __restrict__ ws) {
  int idx = blockIdx.x * blockDim.x + threadIdx.x;
  if (idx < 200 * 64) {
    int nr = idx >> 6, c = idx & 63;
    int j = nr >> 2, gate = nr & 3, r = gate * 50 + j;
    float v = 0.f;
    if (c < 8) v = Wih1[r * 8 + c];
    else if (c < 58) v = Whh1[r * 50 + (c - 8)];
    else if (c == 58) v = bih1[r] + bhh1[r];
    ws[WC1_OFF + idx] = v;
  }
  if (idx < 200 * 128) {
    int nr = idx >> 7, c = idx & 127;
    int j = nr >> 2, gate = nr & 3, r = gate * 50 + j;
    float v = 0.f;
    if (c < 50) v = Wih2[r * 50 + c];
    else if (c < 100) v = Whh2[r * 50 + (c - 50)];
    else if (c == 100) v = bih2[r] + bhh2[r];
    ws[WC2_OFF + idx] = v;
  }
}

__device__ __forceinline__ float sigm(float x) {
  return __builtin_amdgcn_rcpf(1.f + __expf(-x));
}
__device__ __forceinline__ float tanh_(float x) {
  return 1.f - 2.f * __builtin_amdgcn_rcpf(1.f + __expf(2.f * x));
}
__device__ __forceinline__ void bar() {
  asm volatile("s_waitcnt lgkmcnt(0)\n\ts_barrier" ::: "memory");
}
template<int CTRL>
__device__ __forceinline__ float dpp_add(float x) {
  int y = __builtin_amdgcn_mov_dpp(__float_as_int(x), CTRL, 0xF, 0xF, true);
  return x + __int_as_float(y);
}
template<int CTRL>
__device__ __forceinline__ float dpp_mov(float x) {
  return __int_as_float(__builtin_amdgcn_mov_dpp(__float_as_int(x), CTRL, 0xF, 0xF, true));
}
__device__ __forceinline__ float rdlane(float v, int lane) {
  return __int_as_float(__builtin_amdgcn_readlane(__float_as_int(v), lane));
}
__device__ __forceinline__ float swz16(float v) {
  return __int_as_float(__builtin_amdgcn_ds_swizzle(__float_as_int(v), 0x401F));
}

// ============================================================================
// ONE-BARRIER-PER-STEP, 4-wave (256t), row-per-lane design.
// R1..R5 post-mortems: 3 structurally different kernels all ~2240cy/step ->
// the invariant is the sync skeleton (2 barriers + wave-0-only serial phase +
// LDS roundtrips on the chain), not FMA/LDS counts. This kernel:
//  - lane r (=tid, r<200) holds BOTH weight rows: Wc2 row (101 f) + Wc1 row
//    (58 f) in registers (~170 f/lane; waves_per_eu(1,1) -> 512-reg budget).
//  - y/err/gates1/h1/c1 are computed REDUNDANTLY by all 4 waves (bitwise
//    identical) so h1 lives in lanes 0..49 of every wave; the matvecs
//    consume it via v_readlane (VALU pipe, no LDS roundtrip, no barrier).
//  - cross-wave data (PART rows, h2, wo*h2, x) is double-buffered in LDS and
//    crosses exactly ONE barrier per step.
// Step t does: y(t-1) [butterfly of WYB], err(t-1), gates1(t)=PART+werr*err
// -> h1(t), m2a/m1a via readlane(h1), m2b from H2B (h2(t-1)), gates2 -> h2(t),
// m1 rows(t+1) -> PART', h2 -> H2B', wo*h2 -> WYB', loader publishes x.
// ============================================================================

__launch_bounds__(NTHREADS)
__attribute__((amdgpu_waves_per_eu(1, 1)))
__global__ void lstm_kernel(const float* __restrict__ xseq,
                            const float* __restrict__ ws,
                            const float* __restrict__ Wout,
                            const float* __restrict__ bout,
                            float* __restrict__ out) {
  __shared__ __align__(16) float PART[2][256];  // gates1 rows (sans err term)
  __shared__ __align__(16) float H2B[2][52];    // h2 dense (50) + zero pad
  __shared__ __align__(16) float WYB[2][64];    // wo[u]*h2[u], 50..63 = 0
  __shared__ __align__(16) float XB[2][8];      // x(t+1) features 0..6
  __shared__ float ACT4[4];                     // act_dist ring, depth 4

  const int tid  = threadIdx.x;
  const int l    = tid & 63;                    // per-wave unit (gates1 role)
  const int u    = tid >> 2;                    // h2-owner unit
  const bool own2 = ((tid & 3) == 0) && (tid < 200);

  const float* Wc1 = ws + WC1_OFF;
  const float* Wc2 = ws + WC2_OFF;

  for (int i = tid; i < 2 * 256; i += NTHREADS) ((float*)PART)[i] = 0.f;
  for (int i = tid; i < 2 * 52;  i += NTHREADS) ((float*)H2B)[i]  = 0.f;
  for (int i = tid; i < 2 * 64;  i += NTHREADS) ((float*)WYB)[i]  = 0.f;
  for (int i = tid; i < 2 * 8;   i += NTHREADS) ((float*)XB)[i]   = 0.f;
  if (tid < 4) ACT4[tid] = 0.f;

  // ---- register-resident weights (row r = tid; dead rows r>=200 -> 0) ----
  float W2A[50], W2B[50], W1H[50], W1X[7];
  float b1 = 0.f, b2 = 0.f, wo = 0.f, bo;
  float we0 = 0.f, we1 = 0.f, we2 = 0.f, we3 = 0.f;
  #pragma unroll
  for (int c = 0; c < 50; c++) { W2A[c] = 0.f; W2B[c] = 0.f; W1H[c] = 0.f; }
  #pragma unroll
  for (int c = 0; c < 7; c++) W1X[c] = 0.f;
  if (tid < 200) {
    #pragma unroll
    for (int c = 0; c < 50; c++) {
      W2A[c] = Wc2[tid * 128 + c];
      W2B[c] = Wc2[tid * 128 + 50 + c];
      W1H[c] = Wc1[tid * 64 + 8 + c];
    }
    #pragma unroll
    for (int c = 0; c < 7; c++) W1X[c] = Wc1[tid * 64 + c];
    b1 = Wc1[tid * 64 + 58];
    b2 = Wc2[tid * 128 + 100];
  }
  if (own2 && u < 50) wo = Wout[u];
  bo = bout[0];
  if (l < 50) {                                  // redundant in every wave
    we0 = Wc1[(4 * l + 0) * 64 + 7];
    we1 = Wc1[(4 * l + 1) * 64 + 7];
    we2 = Wc1[(4 * l + 2) * 64 + 7];
    we3 = Wc1[(4 * l + 3) * 64 + 7];
  }
  // unified activation for gates2 row (gate = tid&3 ; gate 2 (g) = tanh)
  float sA = -1.f, aA = 0.f, bA = 1.f;
  if ((tid & 3) == 2) { sA = 2.f; aA = 1.f; bA = -2.f; }

  float c1 = 0.f, c2 = 0.f, err = 0.f, h1r = 0.f, xr = 0.f;

  __syncthreads();
  // ---- prologue LDS content (after zeroing) ----
  if (tid < 7)  XB[0][tid] = xseq[8 + tid];      // x(1)
  if (tid == 8) ACT4[0] = xseq[7];               // act(0)
  if (tid == 9) ACT4[1] = xseq[15];              // act(1)
  if (tid >= 248) xr = xseq[16 + (tid - 248)];   // x(2) components
  {
    float s1 = b1;                               // PART for step 0:
    #pragma unroll                               //   W1X*x(0)+b (h1(-1)=0)
    for (int c = 0; c < 7; c++) s1 += W1X[c] * xseq[c];
    PART[0][tid] = s1;
  }
  __syncthreads();

  #pragma unroll 1
  for (int t = 0; t < T; t++) {
    const int par = t & 1;
    // ---------- front-loaded LDS reads ----------
    const float4* H4 = (const float4*)H2B[par];
    float  wyv  = WYB[par][l];
    float4 pq   = *(const float4*)&PART[par][4 * l];
    float  actd = ACT4[(t + 3) & 3];             // == (t-1)&3
    float4 xq0  = *(const float4*)&XB[par][0];
    float4 xq1  = *(const float4*)&XB[par][4];
    // ---------- y(t-1), err(t-1) (redundant, all lanes) ----------
    if (t > 0) {
      float v = wyv;
      v = dpp_add<0xB1>(v); v = dpp_add<0x4E>(v);
      v = dpp_add<0x141>(v); v = dpp_add<0x140>(v);
      v = v + swz16(v);
      float y = rdlane(v, 0) + rdlane(v, 32) + bo;
      if (tid == 0) out[t - 1] = y;              // fire-and-forget
      err = 0.9f * err + 0.1f * (actd - y);
    }
    // ---------- gates1(t) -> h1(t), c1 (redundant per wave) ----------
    {
      float gi = sigm (pq.x + we0 * err);
      float gf = sigm (pq.y + we1 * err);
      float gg = tanh_(pq.z + we2 * err);
      float go = sigm (pq.w + we3 * err);
      c1 = gf * c1 + gi * gg;
      h1r = go * tanh_(c1);
    }
    // ---------- m2b = W2B * h2(t-1) + b2 (independent filler) ----------
    float m2b = b2;
    #pragma unroll
    for (int i = 0; i < 13; i++) {
      float4 h4 = H4[i];
      if (4 * i + 0 < 50) m2b += W2B[4 * i + 0] * h4.x;
      if (4 * i + 1 < 50) m2b += W2B[4 * i + 1] * h4.y;
      if (4 * i + 2 < 50) m2b += W2B[4 * i + 2] * h4.z;
      if (4 * i + 3 < 50) m2b += W2B[4 * i + 3] * h4.w;
    }
    // ---------- m1b = W1X * x(t+1) + b1 ----------
    float m1b = b1;
    m1b += W1X[0] * xq0.x; m1b += W1X[1] * xq0.y;
    m1b += W1X[2] * xq0.z; m1b += W1X[3] * xq0.w;
    m1b += W1X[4] * xq1.x; m1b += W1X[5] * xq1.y;
    m1b += W1X[6] * xq1.z;
    // ---------- m2a/m1a via readlane broadcast of h1(t) ----------
    float a2[4] = {0.f, 0.f, 0.f, 0.f};
    float a1[4] = {0.f, 0.f, 0.f, 0.f};
    #pragma unroll
    for (int c = 0; c < 50; c++) {
      float hc = rdlane(h1r, c);                 // lane c of OWN wave
      a2[c & 3] += W2A[c] * hc;
      a1[c & 3] += W1H[c] * hc;
    }
    float m2a = (a2[0] + a2[1]) + (a2[2] + a2[3]);
    float m1a = (a1[0] + a1[1]) + (a1[2] + a1[3]);
    // ---------- gates2 -> h2(t) (owner lanes unique) ----------
    float s2   = m2a + m2b;
    float actg = aA + bA * __builtin_amdgcn_rcpf(1.f + __expf(sA * s2));
    float x1 = dpp_mov<0xB1>(actg);
    float x2 = dpp_mov<0x4E>(actg);
    float x3 = dpp_mov<0x4E>(x1);
    if (own2) {
      c2 = x1 * c2 + actg * x2;                  // f*c2 + i*g
      float h2v = x3 * tanh_(c2);                // o*tanh(c2)
      H2B[par ^ 1][u] = h2v;
      WYB[par ^ 1][u] = wo * h2v;
    }
    // ---------- m1 rows(t+1) -> PART' ----------
    PART[par ^ 1][tid] = m1a + m1b;              // dead rows: 0
    // ---------- loader (lanes 248..255, dead rows) ----------
    if (tid >= 248) {
      int c = tid - 248;
      if (c < 7) XB[par ^ 1][c] = xr; else ACT4[(t + 2) & 3] = xr;
      int nt = (t + 3 < T) ? t + 3 : T - 1;
      xr = xseq[nt * 8 + c];
    }
    bar();                                        // the ONE barrier
  }
  // ---- epilogue: y(T-1) from WYB[T&1] (T even -> buffer 0) ----
  {
    float v = WYB[0][l];
    v = dpp_add<0xB1>(v); v = dpp_add<0x4E>(v);
    v = dpp_add<0x141>(v); v = dpp_add<0x140>(v);
    v = v + swz16(v);
    float y = rdlane(v, 0) + rdlane(v, 32) + bo;
    if (tid == 0) out[T - 1] = y;
  }
}

extern "C" void kernel_launch(void* const* d_in, const int* in_sizes, int n_in,
                              void* d_out, int out_size, void* d_ws, size_t ws_size,
                              hipStream_t stream) {
  const float* xseq = (const float*)d_in[0];
  const float* Wih1 = (const float*)d_in[1];
  const float* Whh1 = (const float*)d_in[2];
  const float* bih1 = (const float*)d_in[3];
  const float* bhh1 = (const float*)d_in[4];
  const float* Wih2 = (const float*)d_in[5];
  const float* Whh2 = (const float*)d_in[6];
  const float* bih2 = (const float*)d_in[7];
  const float* bhh2 = (const float*)d_in[8];
  const float* Wout = (const float*)d_in[9];
  const float* bout = (const float*)d_in[10];
  float* ws = (float*)d_ws;

  prep_kernel<<<100, 256, 0, stream>>>(Wih1, Whh1, bih1, bhh1,
                                       Wih2, Whh2, bih2, bhh2, ws);
  lstm_kernel<<<1, NTHREADS, 0, stream>>>(xseq, ws, Wout, bout, (float*)d_out);
}